// Round 6
// baseline (454.798 us; speedup 1.0000x reference)
//
#include <hip/hip_runtime.h>

#define NT 150      // trees
#define NPT 341     // nodes per tree
#define LEAF0 85    // first leaf local index
#define NL (NT*256) // 38400 leaves
#define NN (NT*NPT) // 51150 nodes
#define VOCAB 10000

typedef __attribute__((ext_vector_type(8))) short short8;
typedef __attribute__((ext_vector_type(4))) float floatx4;

__device__ __forceinline__ float sigf(float x){ return 1.0f/(1.0f+__expf(-x)); }
__device__ __forceinline__ float bf2f(ushort u){ union{unsigned i; float f;} v; v.i = ((unsigned)u)<<16; return v.f; }
__device__ __forceinline__ ushort f2bf(float x){ union{float f; unsigned i;} v; v.f = x; return (ushort)((v.i + 0x7fff + ((v.i>>16)&1))>>16); }

// ---------- weights transpose+convert: fp32 [256][N] -> bf16 [N][256] -------
__global__ __launch_bounds__(256) void convW_k(
    const float* __restrict__ W1, const float* __restrict__ U1, const float* __restrict__ F1,
    const float* __restrict__ W2, const float* __restrict__ U2, const float* __restrict__ F2,
    ushort* Wt1, ushort* Ut1, ushort* Ft1, ushort* Wt2, ushort* Ut2, ushort* Ft2){
  __shared__ float T[32][33];
  const float* src; ushort* dst; int N;
  switch (blockIdx.z){
    case 0: src=W1; dst=Wt1; N=768; break;
    case 1: src=U1; dst=Ut1; N=768; break;
    case 2: src=F1; dst=Ft1; N=256; break;
    case 3: src=W2; dst=Wt2; N=768; break;
    case 4: src=U2; dst=Ut2; N=768; break;
    default: src=F2; dst=Ft2; N=256; break;
  }
  int n0 = blockIdx.x*32; if (n0 >= N) return;
  int k0 = blockIdx.y*32;
  int nl = threadIdx.x & 31, kb = threadIdx.x >> 5;
  #pragma unroll
  for (int i=0;i<4;i++){ int kk = kb*4+i; T[kk][nl] = src[(size_t)(k0+kk)*N + n0 + nl]; }
  __syncthreads();
  #pragma unroll
  for (int i=0;i<4;i++){ int nn = kb*4+i; dst[(size_t)(n0+nn)*256 + k0 + nl] = f2bf(T[nl][nn]); }
}

// ---------- embedding tables fp32 -> bf16 (elementwise) ---------------------
__global__ __launch_bounds__(256) void convE_k(
    const float* __restrict__ e1, const float* __restrict__ e2,
    ushort* __restrict__ E1, ushort* __restrict__ E2){
  const float* s = blockIdx.y ? e2 : e1;
  ushort* d = blockIdx.y ? E2 : E1;
  size_t i = ((size_t)blockIdx.x*256 + threadIdx.x)*4;
  float4 v = *(const float4*)&s[i];
  d[i+0]=f2bf(v.x); d[i+1]=f2bf(v.y); d[i+2]=f2bf(v.z); d[i+3]=f2bf(v.w);
}

// ---------- fused embed + leaf GEMM: 64 leaves x 768 outputs, 1024 thr ------
__global__ __launch_bounds__(1024) void leaf_k(
    const int* __restrict__ f1, const int* __restrict__ f2,
    const ushort* __restrict__ E1, const ushort* __restrict__ E2,
    const ushort* __restrict__ Wt1, const float* __restrict__ b1,
    const ushort* __restrict__ Wt2, const float* __restrict__ b2,
    ushort* __restrict__ h1, ushort* __restrict__ c1,
    ushort* __restrict__ h2, ushort* __restrict__ c2){
  __shared__ __attribute__((aligned(16))) ushort As[8][64*40];
  int br = blockIdx.y;
  const int* feat = br ? f2 : f1;
  const ushort* E = br ? E2 : E1;
  const ushort* Wt = br ? Wt2 : Wt1;
  const float* biou = br ? b2 : b1;
  ushort* h = br ? h2 : h1;
  ushort* c = br ? c2 : c1;
  int tid = threadIdx.x;
  int lane = tid & 63, wav = tid >> 6, quad = lane >> 4, l15 = lane & 15;
  int rowbase = blockIdx.x*64;

  { // gather + subtoken-mean straight into the A tile (one barrier)
    int row = tid >> 4, seg = tid & 15;
    int leaf = rowbase + row;
    int tree = leaf >> 8;
    size_t node = (size_t)tree*NPT + LEAF0 + (leaf & 255);
    const int* f = feat + node*8;
    float s[16];
    #pragma unroll
    for (int q=0;q<16;q++) s[q]=0.f;
    #pragma unroll
    for (int j=0;j<8;j++){
      const ushort* rp = E + (size_t)f[j]*256 + seg*16;
      short8 a = *(const short8*)rp;
      short8 b = *(const short8*)(rp+8);
      #pragma unroll
      for (int q=0;q<8;q++){ s[q]+=bf2f((ushort)a[q]); s[8+q]+=bf2f((ushort)b[q]); }
    }
    short8 o1, o2;
    #pragma unroll
    for (int q=0;q<8;q++){ o1[q]=(short)f2bf(s[q]*0.125f); o2[q]=(short)f2bf(s[8+q]*0.125f); }
    int cch = seg >> 1, off = (seg & 1)*16;
    *(short8*)&As[cch][row*40 + off]     = o1;
    *(short8*)&As[cch][row*40 + off + 8] = o2;
  }
  __syncthreads();

  floatx4 acc[3][4];
  #pragma unroll
  for (int g=0;g<3;g++)
    #pragma unroll
    for (int r=0;r<4;r++) acc[g][r] = (floatx4){0.f,0.f,0.f,0.f};

  const ushort* bp0 = Wt + (size_t)(0*256 + wav*16 + l15)*256 + quad*8;
  const ushort* bp1 = Wt + (size_t)(1*256 + wav*16 + l15)*256 + quad*8;
  const ushort* bp2 = Wt + (size_t)(2*256 + wav*16 + l15)*256 + quad*8;

  #pragma unroll
  for (int cch=0; cch<8; cch++){
    short8 b0 = *(const short8*)(bp0 + cch*32);
    short8 b1 = *(const short8*)(bp1 + cch*32);
    short8 b2 = *(const short8*)(bp2 + cch*32);
    #pragma unroll
    for (int r=0;r<4;r++){
      short8 a = *(const short8*)&As[cch][(16*r + l15)*40 + quad*8];
      acc[0][r] = __builtin_amdgcn_mfma_f32_16x16x32_bf16(a, b0, acc[0][r], 0,0,0);
      acc[1][r] = __builtin_amdgcn_mfma_f32_16x16x32_bf16(a, b1, acc[1][r], 0,0,0);
      acc[2][r] = __builtin_amdgcn_mfma_f32_16x16x32_bf16(a, b2, acc[2][r], 0,0,0);
    }
  }
  int hc = wav*16 + l15;
  float bi = biou[hc], bo = biou[256+hc], bu = biou[512+hc];
  #pragma unroll
  for (int r=0;r<4;r++){
    #pragma unroll
    for (int reg=0;reg<4;reg++){
      int leaf = rowbase + 16*r + quad*4 + reg;
      int tree = leaf >> 8;
      size_t node = (size_t)tree*NPT + LEAF0 + (leaf & 255);
      float iv = acc[0][r][reg] + bi;
      float ov = acc[1][r][reg] + bo;
      float uv = acc[2][r][reg] + bu;
      float cc = sigf(iv)*tanhf(uv);
      float hh = sigf(ov)*tanhf(cc);
      h[node*256 + hc] = f2bf(hh);
      c[node*256 + hc] = f2bf(cc);
    }
  }
}

// ---------- internal level: NO LDS, NO barrier, A-frags direct from global --
// MFMA A-operand layout (row=lane&15, k-chunk=quad*8) == a 16B global load
// from row-major h; children of consecutive nodes are contiguous so each 64B
// line feeds 4 lanes (L1 serves the 4-wave reuse). Per-child MFMA for all 4
// matrices; child reduction register-local; c prefetched before MFMA loop.
__global__ __launch_bounds__(256) void level_k(
    const ushort* __restrict__ Ut1, const ushort* __restrict__ Ft1,
    const float* __restrict__ Ufb1, const float* __restrict__ bi1,
    const ushort* __restrict__ Ut2, const ushort* __restrict__ Ft2,
    const float* __restrict__ Ufb2, const float* __restrict__ bi2,
    ushort* __restrict__ h1, ushort* __restrict__ c1,
    ushort* __restrict__ h2, ushort* __restrict__ c2,
    int M, int shift, int base){
  int br = blockIdx.z;
  const ushort* Ut = br ? Ut2 : Ut1;
  const ushort* Ft = br ? Ft2 : Ft1;
  const float* Ufb = br ? Ufb2 : Ufb1;
  const float* biou = br ? bi2 : bi1;
  ushort* h = br ? h2 : h1;
  ushort* c = br ? c2 : c1;
  int tid = threadIdx.x;
  int lane = tid & 63, wav = tid >> 6, quad = lane >> 4, l15 = lane & 15;
  int m0 = blockIdx.x*16, cb = blockIdx.y;
  int mask = (1<<shift)-1;
  int col = cb*64 + wav*16 + l15;

  // per-lane A-row pointers: MFMA subtile r needs row 16r+l15, k-chunk quad*8
  const ushort* arow[4];
  #pragma unroll
  for (int r=0;r<4;r++){
    int row = 16*r + l15;
    int m = m0 + (row>>2); if (m > M-1) m = M-1;
    int tree = m >> shift, loc = base + (m & mask);
    arow[r] = h + ((size_t)tree*NPT + 4*loc + 1 + (row&3))*256 + quad*8;
  }

  // prefetch child c values (rows 16r+4*quad+reg at this col) into registers
  float cv[4][4];
  #pragma unroll
  for (int r=0;r<4;r++){
    int m = m0 + 4*r + quad; int mm = m < M ? m : M-1;
    int tree = mm >> shift, loc = base + (mm & mask);
    const ushort* cp = c + ((size_t)tree*NPT + 4*loc + 1)*256 + col;
    #pragma unroll
    for (int reg=0;reg<4;reg++) cv[r][reg] = bf2f(cp[(size_t)reg*256]);
  }

  const ushort* bfp = Ft + (size_t)col*256 + quad*8;
  const ushort* bp0 = Ut + (size_t)(0*256 + col)*256 + quad*8;
  const ushort* bp1 = Ut + (size_t)(256 + col)*256 + quad*8;
  const ushort* bp2 = Ut + (size_t)(512 + col)*256 + quad*8;

  floatx4 af[4], ai[4], ao[4], au[4];
  #pragma unroll
  for (int r=0;r<4;r++){
    af[r] = (floatx4){0.f,0.f,0.f,0.f}; ai[r] = (floatx4){0.f,0.f,0.f,0.f};
    ao[r] = (floatx4){0.f,0.f,0.f,0.f}; au[r] = (floatx4){0.f,0.f,0.f,0.f};
  }

  #pragma unroll
  for (int cc=0; cc<8; cc++){
    short8 Bf = *(const short8*)(bfp + cc*32);
    short8 Bi = *(const short8*)(bp0 + cc*32);
    short8 Bo = *(const short8*)(bp1 + cc*32);
    short8 Bu = *(const short8*)(bp2 + cc*32);
    #pragma unroll
    for (int r=0;r<4;r++){
      short8 a = *(const short8*)(arow[r] + cc*32);
      af[r] = __builtin_amdgcn_mfma_f32_16x16x32_bf16(a, Bf, af[r], 0,0,0);
      ai[r] = __builtin_amdgcn_mfma_f32_16x16x32_bf16(a, Bi, ai[r], 0,0,0);
      ao[r] = __builtin_amdgcn_mfma_f32_16x16x32_bf16(a, Bo, ao[r], 0,0,0);
      au[r] = __builtin_amdgcn_mfma_f32_16x16x32_bf16(a, Bu, au[r], 0,0,0);
    }
  }

  float ufb = Ufb[col];
  float bI = biou[col], bO = biou[256+col], bU = biou[512+col];
  #pragma unroll
  for (int r=0;r<4;r++){
    int m = m0 + 4*r + quad;
    int mm = m < M ? m : M-1;
    int tree = mm >> shift, loc = base + (mm & mask);
    float cs = 0.f;
    #pragma unroll
    for (int reg=0;reg<4;reg++)
      cs += sigf(af[r][reg] + ufb) * cv[r][reg];
    float iv = ai[r][0]+ai[r][1]+ai[r][2]+ai[r][3] + bI;
    float ov = ao[r][0]+ao[r][1]+ao[r][2]+ao[r][3] + bO;
    float uv = au[r][0]+au[r][1]+au[r][2]+au[r][3] + bU;
    float cn = sigf(iv)*tanhf(uv) + cs;
    float hn = sigf(ov)*tanhf(cn);
    if (m < M){
      size_t off = ((size_t)tree*NPT + loc)*256 + col;
      h[off] = f2bf(hn);
      c[off] = f2bf(cn);
    }
  }
}

// ---------- readout partials: sum h over ~85 nodes per (tree,part) ----------
__global__ __launch_bounds__(256) void readout_k(
    const ushort* __restrict__ h1, const ushort* __restrict__ h2,
    float* __restrict__ mp1, float* __restrict__ mp2){
  int br = blockIdx.z, part = blockIdx.y, tree = blockIdx.x;
  const ushort* h = br ? h2 : h1;
  float* mp = br ? mp2 : mp1;
  int t = threadIdx.x;
  int start = part*85;
  int cnt = (part==3) ? 86 : 85;
  const ushort* hp = h + ((size_t)tree*NPT + start)*256 + t;
  float s0=0.f,s1=0.f,s2=0.f,s3=0.f;
  int i = 0;
  for (; i+4<=cnt; i+=4){
    s0 += bf2f(hp[(size_t)(i+0)*256]); s1 += bf2f(hp[(size_t)(i+1)*256]);
    s2 += bf2f(hp[(size_t)(i+2)*256]); s3 += bf2f(hp[(size_t)(i+3)*256]);
  }
  for (; i<cnt; i++) s0 += bf2f(hp[(size_t)i*256]);
  mp[((size_t)tree*4 + part)*256 + t] = s0+s1+s2+s3;
}

// ---------- final: mean->relu->concat@Wf->leaky_relu->softmax ---------------
__global__ __launch_bounds__(64) void final_k(const float* __restrict__ mp1,
    const float* __restrict__ mp2, const float* __restrict__ Wf,
    const float* __restrict__ bf, float* __restrict__ out){
  int tree = blockIdx.x; int t = threadIdx.x;
  float p0=0.f, p1=0.f;
  for (int k=t;k<512;k+=64){
    const float* mp = (k<256) ? mp1 : mp2;
    int kk = k & 255;
    size_t b0 = ((size_t)tree*4)*256 + kk;
    float s = mp[b0] + mp[b0+256] + mp[b0+512] + mp[b0+768];
    float x = fmaxf(s*(1.0f/341.0f), 0.f);
    p0 += x*Wf[k*2+0]; p1 += x*Wf[k*2+1];
  }
  #pragma unroll
  for (int off=32; off>0; off>>=1){
    p0 += __shfl_down(p0, off);
    p1 += __shfl_down(p1, off);
  }
  if (t==0){
    float l0 = p0+bf[0], l1 = p1+bf[1];
    l0 = (l0>0.f)?l0:0.01f*l0;
    l1 = (l1>0.f)?l1:0.01f*l1;
    float mx = fmaxf(l0,l1);
    float e0 = __expf(l0-mx), e1 = __expf(l1-mx);
    float inv = 1.0f/(e0+e1);
    out[tree*2+0] = e0*inv; out[tree*2+1] = e1*inv;
  }
}

extern "C" void kernel_launch(void* const* d_in, const int* in_sizes, int n_in,
                              void* d_out, int out_size, void* d_ws, size_t ws_size,
                              hipStream_t stream) {
  const int*   feat1 = (const int*)  d_in[0];
  const int*   feat2 = (const int*)  d_in[1];
  const float* emb1  = (const float*)d_in[2];
  const float* emb2  = (const float*)d_in[3];
  const float* Wiou1 = (const float*)d_in[4];
  const float* Wiou2 = (const float*)d_in[5];
  const float* Uiou1 = (const float*)d_in[6];
  const float* Uiou2 = (const float*)d_in[7];
  const float* UfW1  = (const float*)d_in[8];
  const float* Ufb1  = (const float*)d_in[9];
  const float* UfW2  = (const float*)d_in[10];
  const float* Ufb2  = (const float*)d_in[11];
  const float* biou1 = (const float*)d_in[12];
  const float* biou2 = (const float*)d_in[13];
  const float* Wf    = (const float*)d_in[14];
  const float* bfv   = (const float*)d_in[15];
  float* out = (float*)d_out;

  char* ws = (char*)d_ws;
  ushort* h1  = (ushort*)ws;  ws += (size_t)NN*256*2;   // 26.2 MB
  ushort* h2  = (ushort*)ws;  ws += (size_t)NN*256*2;
  ushort* c1  = (ushort*)ws;  ws += (size_t)NN*256*2;
  ushort* c2  = (ushort*)ws;  ws += (size_t)NN*256*2;
  ushort* E1  = (ushort*)ws;  ws += (size_t)VOCAB*256*2; // 5.12 MB
  ushort* E2  = (ushort*)ws;  ws += (size_t)VOCAB*256*2;
  ushort* Wt1 = (ushort*)ws;  ws += 768*256*2;
  ushort* Ut1 = (ushort*)ws;  ws += 768*256*2;
  ushort* Ft1 = (ushort*)ws;  ws += 256*256*2;
  ushort* Wt2 = (ushort*)ws;  ws += 768*256*2;
  ushort* Ut2 = (ushort*)ws;  ws += 768*256*2;
  ushort* Ft2 = (ushort*)ws;  ws += 256*256*2;
  float*  mp1 = (float*)ws;   ws += (size_t)NT*4*256*4;
  float*  mp2 = (float*)ws;   ws += (size_t)NT*4*256*4;

  convE_k<<<dim3(2500, 2), 256, 0, stream>>>(emb1, emb2, E1, E2);
  convW_k<<<dim3(24, 8, 6), 256, 0, stream>>>(Wiou1, Uiou1, UfW1, Wiou2, Uiou2, UfW2,
                                              Wt1, Ut1, Ft1, Wt2, Ut2, Ft2);
  leaf_k<<<dim3(NL/64, 2), 1024, 0, stream>>>(feat1, feat2, E1, E2,
                                              Wt1, biou1, Wt2, biou2, h1, c1, h2, c2);

  const int lvlM[4]     = {9600, 2400, 600, 150};
  const int lvlShift[4] = {6, 4, 2, 0};
  const int lvlBase[4]  = {21, 5, 1, 0};
  for (int l=0;l<4;l++){
    int gx = (lvlM[l] + 15)/16;
    level_k<<<dim3(gx, 4, 2), 256, 0, stream>>>(Ut1, Ft1, Ufb1, biou1,
                                                Ut2, Ft2, Ufb2, biou2,
                                                h1, c1, h2, c2,
                                                lvlM[l], lvlShift[l], lvlBase[l]);
  }
  readout_k<<<dim3(NT, 4, 2), 256, 0, stream>>>(h1, h2, mp1, mp2);
  final_k<<<NT, 64, 0, stream>>>(mp1, mp2, Wf, bfv, out);
}

// Round 7
// 388.872 us; speedup vs baseline: 1.1695x; 1.1695x over previous
//
#include <hip/hip_runtime.h>

#define NT 150      // trees
#define NPT 341     // nodes per tree
#define VOCAB 10000

typedef __attribute__((ext_vector_type(8))) short short8;
typedef __attribute__((ext_vector_type(4))) float floatx4;

__device__ __forceinline__ float sigf(float x){ return 1.0f/(1.0f+__expf(-x)); }
__device__ __forceinline__ float bf2f(ushort u){ union{unsigned i; float f;} v; v.i = ((unsigned)u)<<16; return v.f; }
__device__ __forceinline__ ushort f2bf(float x){ union{float f; unsigned i;} v; v.f = x; return (ushort)((v.i + 0x7fff + ((v.i>>16)&1))>>16); }

// ---------- weights transpose+convert: fp32 [256][N] -> bf16 [N][256] -------
__global__ __launch_bounds__(256) void convW_k(
    const float* __restrict__ W1, const float* __restrict__ U1, const float* __restrict__ F1,
    const float* __restrict__ W2, const float* __restrict__ U2, const float* __restrict__ F2,
    ushort* Wt1, ushort* Ut1, ushort* Ft1, ushort* Wt2, ushort* Ut2, ushort* Ft2){
  __shared__ float T[32][33];
  const float* src; ushort* dst; int N;
  switch (blockIdx.z){
    case 0: src=W1; dst=Wt1; N=768; break;
    case 1: src=U1; dst=Ut1; N=768; break;
    case 2: src=F1; dst=Ft1; N=256; break;
    case 3: src=W2; dst=Wt2; N=768; break;
    case 4: src=U2; dst=Ut2; N=768; break;
    default: src=F2; dst=Ft2; N=256; break;
  }
  int n0 = blockIdx.x*32; if (n0 >= N) return;
  int k0 = blockIdx.y*32;
  int nl = threadIdx.x & 31, kb = threadIdx.x >> 5;
  #pragma unroll
  for (int i=0;i<4;i++){ int kk = kb*4+i; T[kk][nl] = src[(size_t)(k0+kk)*N + n0 + nl]; }
  __syncthreads();
  #pragma unroll
  for (int i=0;i<4;i++){ int nn = kb*4+i; dst[(size_t)(n0+nn)*256 + k0 + nl] = f2bf(T[nl][nn]); }
}

// ---------- embedding tables fp32 -> bf16 (elementwise) ---------------------
__global__ __launch_bounds__(256) void convE_k(
    const float* __restrict__ e1, const float* __restrict__ e2,
    ushort* __restrict__ E1, ushort* __restrict__ E2){
  const float* s = blockIdx.y ? e2 : e1;
  ushort* d = blockIdx.y ? E2 : E1;
  size_t i = ((size_t)blockIdx.x*256 + threadIdx.x)*4;
  float4 v = *(const float4*)&s[i];
  d[i+0]=f2bf(v.x); d[i+1]=f2bf(v.y); d[i+2]=f2bf(v.z); d[i+3]=f2bf(v.w);
}

// ---------- Kernel A: embed + leaf + l0, per 64-leaf subtree ----------------
// block = 1024 threads (16 waves), grid (600, 2br). Leaf h,c stay on-chip.
// Outputs: l0 h,c (16 nodes) to global; subtree col-sum partial (80 rows).
__global__ __launch_bounds__(1024) void subtree_k(
    const int* __restrict__ f1, const int* __restrict__ f2,
    const ushort* __restrict__ E1, const ushort* __restrict__ E2,
    const ushort* __restrict__ Wt1, const float* __restrict__ b1,
    const ushort* __restrict__ Ut1, const ushort* __restrict__ Ft1, const float* __restrict__ Ufb1,
    const ushort* __restrict__ Wt2, const float* __restrict__ b2,
    const ushort* __restrict__ Ut2, const ushort* __restrict__ Ft2, const float* __restrict__ Ufb2,
    ushort* __restrict__ h1, ushort* __restrict__ c1,
    ushort* __restrict__ h2, ushort* __restrict__ c2,
    float* __restrict__ part){
  __shared__ __attribute__((aligned(16))) ushort As[8][64*40];
  __shared__ __attribute__((aligned(16))) ushort Ht[8][16*40];
  __shared__ float Csum[16][272];
  int br = blockIdx.y;
  const int* feat = br ? f2 : f1;
  const ushort* E = br ? E2 : E1;
  const ushort* Wt = br ? Wt2 : Wt1;
  const float* biou = br ? b2 : b1;
  const ushort* Ut = br ? Ut2 : Ut1;
  const ushort* Ft = br ? Ft2 : Ft1;
  const float* Ufb = br ? Ufb2 : Ufb1;
  ushort* h = br ? h2 : h1;
  ushort* c = br ? c2 : c1;
  int s = blockIdx.x;
  int tree = s >> 2, j = s & 3;
  size_t nbase = (size_t)tree*NPT;
  int tid = threadIdx.x, lane = tid & 63, wav = tid >> 6, quad = lane >> 4, l15 = lane & 15;

  { // --- embed: gather-mean straight into As ---
    int row = tid >> 4, seg = tid & 15;
    size_t node = nbase + 85 + 64*j + row;
    const int* f = feat + node*8;
    float sm[16];
    #pragma unroll
    for (int q=0;q<16;q++) sm[q]=0.f;
    #pragma unroll
    for (int t8=0;t8<8;t8++){
      const ushort* rp = E + (size_t)f[t8]*256 + seg*16;
      short8 a = *(const short8*)rp;
      short8 b = *(const short8*)(rp+8);
      #pragma unroll
      for (int q=0;q<8;q++){ sm[q]+=bf2f((ushort)a[q]); sm[8+q]+=bf2f((ushort)b[q]); }
    }
    short8 o1, o2;
    #pragma unroll
    for (int q=0;q<8;q++){ o1[q]=(short)f2bf(sm[q]*0.125f); o2[q]=(short)f2bf(sm[8+q]*0.125f); }
    int cch = seg >> 1, off = (seg & 1)*16;
    *(short8*)&As[cch][row*40 + off]     = o1;
    *(short8*)&As[cch][row*40 + off + 8] = o2;
  }
  __syncthreads();

  int hcol = wav*16 + l15;         // this lane's hidden column 0..255
  int cch = hcol >> 5, coff = hcol & 31;
  float bi = biou[hcol], bo = biou[256+hcol], bu = biou[512+hcol];

  // --- leaf GEMM ---
  floatx4 acc[3][4];
  #pragma unroll
  for (int g=0;g<3;g++)
    #pragma unroll
    for (int r=0;r<4;r++) acc[g][r] = (floatx4){0.f,0.f,0.f,0.f};
  {
    const ushort* bp0 = Wt + (size_t)(0*256 + hcol)*256 + quad*8;
    const ushort* bp1 = Wt + (size_t)(1*256 + hcol)*256 + quad*8;
    const ushort* bp2 = Wt + (size_t)(2*256 + hcol)*256 + quad*8;
    #pragma unroll
    for (int k8=0;k8<8;k8++){
      short8 b0 = *(const short8*)(bp0 + k8*32);
      short8 b1 = *(const short8*)(bp1 + k8*32);
      short8 b2 = *(const short8*)(bp2 + k8*32);
      #pragma unroll
      for (int r=0;r<4;r++){
        short8 a = *(const short8*)&As[k8][(16*r + l15)*40 + quad*8];
        acc[0][r] = __builtin_amdgcn_mfma_f32_16x16x32_bf16(a, b0, acc[0][r], 0,0,0);
        acc[1][r] = __builtin_amdgcn_mfma_f32_16x16x32_bf16(a, b1, acc[1][r], 0,0,0);
        acc[2][r] = __builtin_amdgcn_mfma_f32_16x16x32_bf16(a, b2, acc[2][r], 0,0,0);
      }
    }
  }
  // leaf epilogue: h,c in registers; h_tild per parent register-local
  float hL[4][4], cL[4][4], htd[4];
  #pragma unroll
  for (int r=0;r<4;r++){
    htd[r] = 0.f;
    #pragma unroll
    for (int reg=0;reg<4;reg++){
      float iv = acc[0][r][reg] + bi;
      float ov = acc[1][r][reg] + bo;
      float uv = acc[2][r][reg] + bu;
      float cc_ = sigf(iv)*tanhf(uv);
      float hh = sigf(ov)*tanhf(cc_);
      cL[r][reg] = cc_; hL[r][reg] = hh; htd[r] += hh;
    }
  }
  __syncthreads();   // all As reads done -> safe to overwrite
  float sA = 0.f;
  #pragma unroll
  for (int r=0;r<4;r++){
    #pragma unroll
    for (int reg=0;reg<4;reg++){
      As[cch][(16*r + quad*4 + reg)*40 + coff] = f2bf(hL[r][reg]);   // leaf h tile
      sA += hL[r][reg];
    }
    Ht[cch][(4*r + quad)*40 + coff] = f2bf(htd[r]);                  // h_tild tile
  }
  __syncthreads();

  // --- l0: forget per-child (A=leaf h) + iou via h_tild (M=16) ---
  floatx4 af[4], ai, ao, au;
  #pragma unroll
  for (int r=0;r<4;r++) af[r] = (floatx4){0.f,0.f,0.f,0.f};
  ai = (floatx4){0.f,0.f,0.f,0.f}; ao = ai; au = ai;
  {
    const ushort* bfp = Ft + (size_t)hcol*256 + quad*8;
    const ushort* up0 = Ut + (size_t)(0*256 + hcol)*256 + quad*8;
    const ushort* up1 = Ut + (size_t)(256 + hcol)*256 + quad*8;
    const ushort* up2 = Ut + (size_t)(512 + hcol)*256 + quad*8;
    #pragma unroll
    for (int k8=0;k8<8;k8++){
      short8 Bf = *(const short8*)(bfp + k8*32);
      short8 B0 = *(const short8*)(up0 + k8*32);
      short8 B1 = *(const short8*)(up1 + k8*32);
      short8 B2 = *(const short8*)(up2 + k8*32);
      short8 ah = *(const short8*)&Ht[k8][l15*40 + quad*8];
      #pragma unroll
      for (int r=0;r<4;r++){
        short8 a = *(const short8*)&As[k8][(16*r + l15)*40 + quad*8];
        af[r] = __builtin_amdgcn_mfma_f32_16x16x32_bf16(a, Bf, af[r], 0,0,0);
      }
      ai = __builtin_amdgcn_mfma_f32_16x16x32_bf16(ah, B0, ai, 0,0,0);
      ao = __builtin_amdgcn_mfma_f32_16x16x32_bf16(ah, B1, ao, 0,0,0);
      au = __builtin_amdgcn_mfma_f32_16x16x32_bf16(ah, B2, au, 0,0,0);
    }
  }
  float ufb = Ufb[hcol];
  #pragma unroll
  for (int r=0;r<4;r++){
    float cs = 0.f;
    #pragma unroll
    for (int reg=0;reg<4;reg++) cs += sigf(af[r][reg] + ufb) * cL[r][reg];
    Csum[4*r + quad][hcol] = cs;     // wave-local write/read (same cols)
  }
  #pragma unroll
  for (int reg=0;reg<4;reg++){
    int p = quad*4 + reg;
    float cs = Csum[p][hcol];
    float iv = ai[reg] + bi, ov = ao[reg] + bo, uv = au[reg] + bu;
    float cn = sigf(iv)*tanhf(uv) + cs;
    float hn = sigf(ov)*tanhf(cn);
    sA += hn;
    size_t off = (nbase + 21 + 16*j + p)*256 + hcol;
    h[off] = f2bf(hn);
    c[off] = f2bf(cn);
  }
  // subtree readout partial (80 rows per col)
  sA += __shfl_xor(sA, 16);
  sA += __shfl_xor(sA, 32);
  if (quad == 0) part[((size_t)(s*2 + br))*256 + hcol] = sA;
}

// ---------- Kernel B: l1 + l2 + root + readout + final, per tree ------------
__global__ __launch_bounds__(1024) void upper_k(
    const ushort* __restrict__ Ut1, const ushort* __restrict__ Ft1,
    const float* __restrict__ Ufb1, const float* __restrict__ b1,
    const ushort* __restrict__ Ut2, const ushort* __restrict__ Ft2,
    const float* __restrict__ Ufb2, const float* __restrict__ b2,
    const ushort* __restrict__ h1, const ushort* __restrict__ c1,
    const ushort* __restrict__ h2, const ushort* __restrict__ c2,
    const float* __restrict__ part, const float* __restrict__ Wf,
    const float* __restrict__ bfv, float* __restrict__ out){
  __shared__ __attribute__((aligned(16))) ushort As[8][64*40];
  __shared__ __attribute__((aligned(16))) ushort Ht[8][16*40];
  __shared__ float Csum[16][272];
  __shared__ float Ms[2][256];
  __shared__ float red[32];
  int tree = blockIdx.x;
  size_t nbase = (size_t)tree*NPT;
  int tid = threadIdx.x, lane = tid & 63, wav = tid >> 6, quad = lane >> 4, l15 = lane & 15;
  int hcol = wav*16 + l15;
  int cch = hcol >> 5, coff = hcol & 31;

  for (int br=0; br<2; br++){
    const ushort* Ut = br ? Ut2 : Ut1;
    const ushort* Ft = br ? Ft2 : Ft1;
    const float* Ufb = br ? Ufb2 : Ufb1;
    const float* biou = br ? b2 : b1;
    const ushort* h = br ? h2 : h1;
    const ushort* c = br ? c2 : c1;
    float bi = biou[hcol], bo = biou[256+hcol], bu = biou[512+hcol];
    float ufb = Ufb[hcol];

    { // stage l0 h (64 nodes, local 21..84)
      int row = tid >> 4, seg = tid & 15;
      const ushort* src = h + (nbase + 21 + row)*256 + seg*16;
      short8 a = *(const short8*)src;
      short8 b = *(const short8*)(src+8);
      int cc2 = seg >> 1, off = (seg & 1)*16;
      *(short8*)&As[cc2][row*40 + off]     = a;
      *(short8*)&As[cc2][row*40 + off + 8] = b;
    }
    // prefetch l0 c values (children of l1 nodes)
    float cL0[4][4];
    #pragma unroll
    for (int r=0;r<4;r++)
      #pragma unroll
      for (int reg=0;reg<4;reg++)
        cL0[r][reg] = bf2f(c[(nbase + 21 + 16*r + quad*4 + reg)*256 + hcol]);
    __syncthreads();
    // h_tild (16 x 256) from As
    if (tid < 512){
      int n = tid >> 5, sg = tid & 31;
      int cc2 = sg >> 2, off = (sg & 3)*8;
      float s8[8];
      #pragma unroll
      for (int q=0;q<8;q++) s8[q]=0.f;
      #pragma unroll
      for (int i=0;i<4;i++){
        short8 v = *(const short8*)&As[cc2][(4*n+i)*40 + off];
        #pragma unroll
        for (int q=0;q<8;q++) s8[q] += bf2f((ushort)v[q]);
      }
      short8 o;
      #pragma unroll
      for (int q=0;q<8;q++) o[q] = (short)f2bf(s8[q]);
      *(short8*)&Ht[cc2][n*40 + off] = o;
    }
    __syncthreads();

    const ushort* bfp = Ft + (size_t)hcol*256 + quad*8;
    const ushort* up0 = Ut + (size_t)(0*256 + hcol)*256 + quad*8;
    const ushort* up1 = Ut + (size_t)(256 + hcol)*256 + quad*8;
    const ushort* up2 = Ut + (size_t)(512 + hcol)*256 + quad*8;

    // --- l1: forget per-child (A=As) + iou via h_tild ---
    floatx4 af1[4], ai1, ao1, au1;
    #pragma unroll
    for (int r=0;r<4;r++) af1[r] = (floatx4){0.f,0.f,0.f,0.f};
    ai1 = (floatx4){0.f,0.f,0.f,0.f}; ao1 = ai1; au1 = ai1;
    #pragma unroll
    for (int k8=0;k8<8;k8++){
      short8 Bf = *(const short8*)(bfp + k8*32);
      short8 B0 = *(const short8*)(up0 + k8*32);
      short8 B1 = *(const short8*)(up1 + k8*32);
      short8 B2 = *(const short8*)(up2 + k8*32);
      short8 ah = *(const short8*)&Ht[k8][l15*40 + quad*8];
      #pragma unroll
      for (int r=0;r<4;r++){
        short8 a = *(const short8*)&As[k8][(16*r + l15)*40 + quad*8];
        af1[r] = __builtin_amdgcn_mfma_f32_16x16x32_bf16(a, Bf, af1[r], 0,0,0);
      }
      ai1 = __builtin_amdgcn_mfma_f32_16x16x32_bf16(ah, B0, ai1, 0,0,0);
      ao1 = __builtin_amdgcn_mfma_f32_16x16x32_bf16(ah, B1, ao1, 0,0,0);
      au1 = __builtin_amdgcn_mfma_f32_16x16x32_bf16(ah, B2, au1, 0,0,0);
    }
    #pragma unroll
    for (int r=0;r<4;r++){
      float cs = 0.f;
      #pragma unroll
      for (int reg=0;reg<4;reg++) cs += sigf(af1[r][reg] + ufb) * cL0[r][reg];
      Csum[4*r + quad][hcol] = cs;
    }
    float h1v[4], c1v[4], sB = 0.f;
    #pragma unroll
    for (int reg=0;reg<4;reg++){
      int p = quad*4 + reg;
      float cs = Csum[p][hcol];
      float iv = ai1[reg]+bi, ov = ao1[reg]+bo, uv = au1[reg]+bu;
      c1v[reg] = sigf(iv)*tanhf(uv) + cs;
      h1v[reg] = sigf(ov)*tanhf(c1v[reg]);
      sB += h1v[reg];
    }
    __syncthreads();   // Ht (h_tild) reads done
    #pragma unroll
    for (int reg=0;reg<4;reg++)
      Ht[cch][(quad*4 + reg)*40 + coff] = f2bf(h1v[reg]);   // l1 h (16 rows)
    __syncthreads();

    // --- l2: per-child forget+iou, A = l1 h (16 rows) ---
    floatx4 af2, ai2, ao2, au2;
    af2 = (floatx4){0.f,0.f,0.f,0.f}; ai2 = af2; ao2 = af2; au2 = af2;
    #pragma unroll
    for (int k8=0;k8<8;k8++){
      short8 Bf = *(const short8*)(bfp + k8*32);
      short8 B0 = *(const short8*)(up0 + k8*32);
      short8 B1 = *(const short8*)(up1 + k8*32);
      short8 B2 = *(const short8*)(up2 + k8*32);
      short8 a = *(const short8*)&Ht[k8][l15*40 + quad*8];
      af2 = __builtin_amdgcn_mfma_f32_16x16x32_bf16(a, Bf, af2, 0,0,0);
      ai2 = __builtin_amdgcn_mfma_f32_16x16x32_bf16(a, B0, ai2, 0,0,0);
      ao2 = __builtin_amdgcn_mfma_f32_16x16x32_bf16(a, B1, ao2, 0,0,0);
      au2 = __builtin_amdgcn_mfma_f32_16x16x32_bf16(a, B2, au2, 0,0,0);
    }
    float cs2 = 0.f;
    #pragma unroll
    for (int reg=0;reg<4;reg++) cs2 += sigf(af2[reg] + ufb) * c1v[reg];
    float iv2 = ai2[0]+ai2[1]+ai2[2]+ai2[3] + bi;
    float ov2 = ao2[0]+ao2[1]+ao2[2]+ao2[3] + bo;
    float uv2 = au2[0]+au2[1]+au2[2]+au2[3] + bu;
    float c2v = sigf(iv2)*tanhf(uv2) + cs2;   // l2 node m = quad
    float h2v = sigf(ov2)*tanhf(c2v);
    sB += h2v;
    __syncthreads();
    Ht[cch][quad*40 + coff] = f2bf(h2v);      // l2 h rows 0..3
    #pragma unroll
    for (int z=1;z<4;z++) Ht[cch][(quad + 4*z)*40 + coff] = 0;
    __syncthreads();

    // --- root: per-child, A rows 0..3 valid ---
    floatx4 af3, ai3, ao3, au3;
    af3 = (floatx4){0.f,0.f,0.f,0.f}; ai3 = af3; ao3 = af3; au3 = af3;
    #pragma unroll
    for (int k8=0;k8<8;k8++){
      short8 Bf = *(const short8*)(bfp + k8*32);
      short8 B0 = *(const short8*)(up0 + k8*32);
      short8 B1 = *(const short8*)(up1 + k8*32);
      short8 B2 = *(const short8*)(up2 + k8*32);
      short8 a = *(const short8*)&Ht[k8][l15*40 + quad*8];
      af3 = __builtin_amdgcn_mfma_f32_16x16x32_bf16(a, Bf, af3, 0,0,0);
      ai3 = __builtin_amdgcn_mfma_f32_16x16x32_bf16(a, B0, ai3, 0,0,0);
      ao3 = __builtin_amdgcn_mfma_f32_16x16x32_bf16(a, B1, ao3, 0,0,0);
      au3 = __builtin_amdgcn_mfma_f32_16x16x32_bf16(a, B2, au3, 0,0,0);
    }
    float c2c[4];
    #pragma unroll
    for (int reg=0;reg<4;reg++) c2c[reg] = __shfl(c2v, reg*16 + l15);
    {
      float cs3 = 0.f;
      #pragma unroll
      for (int reg=0;reg<4;reg++) cs3 += sigf(af3[reg] + ufb) * c2c[reg];
      float iv3 = ai3[0]+ai3[1]+ai3[2]+ai3[3] + bi;
      float ov3 = ao3[0]+ao3[1]+ao3[2]+ao3[3] + bo;
      float uv3 = au3[0]+au3[1]+au3[2]+au3[3] + bu;
      float c3 = sigf(iv3)*tanhf(uv3) + cs3;
      float hr = sigf(ov3)*tanhf(c3);
      if (quad == 0) sB += hr;            // root h valid on quad0 lanes only
    }
    sB += __shfl_xor(sB, 16);
    sB += __shfl_xor(sB, 32);
    if (quad == 0){
      float tot = sB;
      #pragma unroll
      for (int jj=0;jj<4;jj++)
        tot += part[((size_t)((tree*4 + jj)*2 + br))*256 + hcol];
      Ms[br][hcol] = fmaxf(tot*(1.0f/341.0f), 0.f);
    }
    __syncthreads();
  }

  // --- final: concat @ Wf -> leaky_relu -> softmax ---
  float p0 = 0.f, p1 = 0.f;
  if (tid < 512){
    float x = Ms[tid >> 8][tid & 255];
    p0 = x*Wf[tid*2+0]; p1 = x*Wf[tid*2+1];
  }
  #pragma unroll
  for (int off=32; off>0; off>>=1){
    p0 += __shfl_down(p0, off);
    p1 += __shfl_down(p1, off);
  }
  if (lane == 0){ red[wav] = p0; red[16+wav] = p1; }
  __syncthreads();
  if (tid == 0){
    float l0 = bfv[0], l1 = bfv[1];
    #pragma unroll
    for (int w=0;w<16;w++){ l0 += red[w]; l1 += red[16+w]; }
    l0 = (l0>0.f)?l0:0.01f*l0;
    l1 = (l1>0.f)?l1:0.01f*l1;
    float mx = fmaxf(l0,l1);
    float e0 = __expf(l0-mx), e1 = __expf(l1-mx);
    float inv = 1.0f/(e0+e1);
    out[tree*2+0] = e0*inv; out[tree*2+1] = e1*inv;
  }
}

extern "C" void kernel_launch(void* const* d_in, const int* in_sizes, int n_in,
                              void* d_out, int out_size, void* d_ws, size_t ws_size,
                              hipStream_t stream) {
  const int*   feat1 = (const int*)  d_in[0];
  const int*   feat2 = (const int*)  d_in[1];
  const float* emb1  = (const float*)d_in[2];
  const float* emb2  = (const float*)d_in[3];
  const float* Wiou1 = (const float*)d_in[4];
  const float* Wiou2 = (const float*)d_in[5];
  const float* Uiou1 = (const float*)d_in[6];
  const float* Uiou2 = (const float*)d_in[7];
  const float* UfW1  = (const float*)d_in[8];
  const float* Ufb1  = (const float*)d_in[9];
  const float* UfW2  = (const float*)d_in[10];
  const float* Ufb2  = (const float*)d_in[11];
  const float* biou1 = (const float*)d_in[12];
  const float* biou2 = (const float*)d_in[13];
  const float* Wf    = (const float*)d_in[14];
  const float* bfv   = (const float*)d_in[15];
  float* out = (float*)d_out;

  char* ws = (char*)d_ws;
  ushort* h1  = (ushort*)ws;  ws += (size_t)NT*NPT*256*2;
  ushort* h2  = (ushort*)ws;  ws += (size_t)NT*NPT*256*2;
  ushort* c1  = (ushort*)ws;  ws += (size_t)NT*NPT*256*2;
  ushort* c2  = (ushort*)ws;  ws += (size_t)NT*NPT*256*2;
  ushort* E1  = (ushort*)ws;  ws += (size_t)VOCAB*256*2;
  ushort* E2  = (ushort*)ws;  ws += (size_t)VOCAB*256*2;
  ushort* Wt1 = (ushort*)ws;  ws += 768*256*2;
  ushort* Ut1 = (ushort*)ws;  ws += 768*256*2;
  ushort* Ft1 = (ushort*)ws;  ws += 256*256*2;
  ushort* Wt2 = (ushort*)ws;  ws += 768*256*2;
  ushort* Ut2 = (ushort*)ws;  ws += 768*256*2;
  ushort* Ft2 = (ushort*)ws;  ws += 256*256*2;
  float*  part = (float*)ws;  ws += (size_t)600*2*256*4;

  convE_k<<<dim3(2500, 2), 256, 0, stream>>>(emb1, emb2, E1, E2);
  convW_k<<<dim3(24, 8, 6), 256, 0, stream>>>(Wiou1, Uiou1, UfW1, Wiou2, Uiou2, UfW2,
                                              Wt1, Ut1, Ft1, Wt2, Ut2, Ft2);
  subtree_k<<<dim3(600, 2), 1024, 0, stream>>>(feat1, feat2, E1, E2,
                                               Wt1, biou1, Ut1, Ft1, Ufb1,
                                               Wt2, biou2, Ut2, Ft2, Ufb2,
                                               h1, c1, h2, c2, part);
  upper_k<<<NT, 1024, 0, stream>>>(Ut1, Ft1, Ufb1, biou1,
                                   Ut2, Ft2, Ufb2, biou2,
                                   h1, c1, h2, c2, part, Wf, bfv, out);
}